// Round 9
// baseline (873.705 us; speedup 1.0000x reference)
//
#include <hip/hip_runtime.h>
#include <hip/hip_bf16.h>

typedef __bf16 bf16_t;
typedef __attribute__((ext_vector_type(8))) __bf16 bf16x8;
typedef __attribute__((ext_vector_type(4))) float floatx4;
typedef __attribute__((ext_vector_type(16))) float floatx16;

// Problem constants: B=4, T=2048, C=2048, H=16, D=128, QKV_DIM=6144, QKVZ=8192, BT=8192

__device__ __forceinline__ void gload16(const void* g, void* l) {
  __builtin_amdgcn_global_load_lds(
      (const __attribute__((address_space(1))) void*)g,
      (__attribute__((address_space(3))) void*)l, 16, 0, 0);
}

// ---------------- cast fp32 -> bf16 (vectorized) ----------------
__global__ __launch_bounds__(256) void k_cast_bf16(const float* __restrict__ in,
                                                   bf16_t* __restrict__ out) {
  long i = ((long)blockIdx.x * 256 + threadIdx.x) * 8;
  const float4 a = *(const float4*)(in + i);
  const float4 b = *(const float4*)(in + i + 4);
  bf16x8 o;
  o[0] = (bf16_t)a.x; o[1] = (bf16_t)a.y; o[2] = (bf16_t)a.z; o[3] = (bf16_t)a.w;
  o[4] = (bf16_t)b.x; o[5] = (bf16_t)b.y; o[6] = (bf16_t)b.z; o[7] = (bf16_t)b.w;
  *(bf16x8*)(out + i) = o;
}

// ---------------- transpose + cast fp32 -> bf16 ----------------
__global__ void k_transpose_cast(const float* __restrict__ in, bf16_t* __restrict__ out,
                                 int R, int Ccols) {
  __shared__ float tile[32][33];
  int c0 = blockIdx.x * 32, r0 = blockIdx.y * 32;
  for (int i = threadIdx.y; i < 32; i += 8)
    tile[i][threadIdx.x] = in[(long)(r0 + i) * Ccols + c0 + threadIdx.x];
  __syncthreads();
  for (int i = threadIdx.y; i < 32; i += 8)
    out[(long)(c0 + i) * R + r0 + threadIdx.x] = (bf16_t)tile[threadIdx.x][i];
}

// small fp32 transpose (for W_b / W_a: 2048x16 -> 16x2048)
__global__ void k_transpose_f32(const float* __restrict__ in, float* __restrict__ out,
                                int R, int Ccols) {
  int r = blockIdx.x * blockDim.x + threadIdx.x;
  if (r < R)
    for (int c = 0; c < Ccols; ++c) out[(long)c * R + r] = in[(long)r * Ccols + c];
}

// ---------------- beta/alpha v2: sigmoid(x @ W), 16 rows/block, x in LDS -------------
// Grid 512 x 256 threads, dynamic LDS 128 KB (x rows fp32). W streamed coalesced from
// L2 once per block (32 rows x 8KB = 256 KB), reused across 16 x-rows in registers.
__global__ __launch_bounds__(256) void k_beta_alpha(const float* __restrict__ x,
                                                    const float* __restrict__ WbT,
                                                    const float* __restrict__ WaT,
                                                    float* __restrict__ beta,
                                                    float* __restrict__ alpha) {
  extern __shared__ float xs[];  // [16][2048]
  const long row0 = (long)blockIdx.x * 16;
  const int tid = threadIdx.x;
  {
    const float4* src = (const float4*)(x + row0 * 2048);
    float4* dst = (float4*)xs;
    for (int i = tid; i < 16 * 512; i += 256) dst[i] = src[i];
  }
  __syncthreads();
  const int wv = tid >> 6, lane = tid & 63;
  for (int oo = 0; oo < 8; ++oo) {
    const int o = wv * 8 + oo;
    const float* Wrow = (o < 16) ? (WbT + (long)o * 2048) : (WaT + (long)(o - 16) * 2048);
    float acc[16];
#pragma unroll
    for (int r = 0; r < 16; ++r) acc[r] = 0.f;
    for (int kc = 0; kc < 8; ++kc) {
      const float4 w4 = *(const float4*)(Wrow + kc * 256 + lane * 4);
#pragma unroll
      for (int r = 0; r < 16; ++r) {
        const float4 xv = *(const float4*)&xs[r * 2048 + kc * 256 + lane * 4];
        acc[r] += w4.x * xv.x + w4.y * xv.y + w4.z * xv.z + w4.w * xv.w;
      }
    }
#pragma unroll
    for (int r = 0; r < 16; ++r) {
      float s = acc[r];
      for (int off = 32; off; off >>= 1) s += __shfl_down(s, off);
      if (lane == 0) {
        const long row = row0 + r;
        const int b = (int)(row >> 11), t = (int)(row & 2047);
        const float sig = 1.f / (1.f + __expf(-s));
        float* dst = (o < 16) ? beta : alpha;
        dst[((long)(b * 16 + (o & 15))) * 2048 + t] = sig;
      }
    }
  }
}

// ---------------- bf16 MFMA GEMM 256x256 (32x32x16 frags): C = A @ Bt^T ---------------
// A: M x K row-major bf16 (row stride lda). Bt: N x K row-major bf16 (ldb = K).
// C: M x N row-major OUT_T. BM=BN=256, BK=64, 512 threads = 8 waves (2M x 4N),
// per-wave 128x64 output = acc[4][2] 32x32 frags (16 f32/lane each). LDS double-buffered
// 128 KiB. T2 swizzle: 16B chunk (row, c) at (row, c ^ (row&7)); linear gload dest +
// inverse-permuted global source (rule 21); reads apply the XOR. Per-quarter-wave reads
// are 8 chunks x 2-way -> conflict-free (measured 0 in the 16x16 variant, same pattern).
// Pipeline: ONE barrier per K-step; STAGE(kt+1 -> other buffer) issued right after the
// barrier, drained by the NEXT barrier => drain covered by a full 32-MFMA compute phase.
template <typename OUT_T>
__global__ __launch_bounds__(512, 2) void k_gemm256(const bf16_t* __restrict__ A,
                                                    const bf16_t* __restrict__ Bt,
                                                    OUT_T* __restrict__ C,
                                                    int N, int K, int lda) {
  extern __shared__ char gsm[];  // [buf0: A 32K | B 32K][buf1: A 32K | B 32K]
  const int m0 = blockIdx.y * 256, n0 = blockIdx.x * 256;
  const int tid = threadIdx.x;
  const int w = tid >> 6, l = tid & 63;
  const int wm = w >> 2, wn = w & 3;
  const int l31 = l & 31, l5 = l >> 5;

  // staging: 4 chunks per matrix per thread; chunk id c = t*512+tid; dest byte c*16
  const bf16_t* asrc[4];
  const bf16_t* bsrc[4];
  int dofs[4];
#pragma unroll
  for (int t = 0; t < 4; ++t) {
    int c = t * 512 + tid;
    int row = c >> 3, cs = (c & 7) ^ (row & 7);  // pre-swizzled source chunk
    asrc[t] = A + (long)(m0 + row) * lda + cs * 8;
    bsrc[t] = Bt + (long)(n0 + row) * K + cs * 8;
    dofs[t] = c * 16;
  }

  auto STAGE = [&](int buf, int k0) {
    char* ab = gsm + buf * 65536;
    char* bb = ab + 32768;
#pragma unroll
    for (int t = 0; t < 4; ++t) {
      gload16(asrc[t] + k0, ab + dofs[t]);
      gload16(bsrc[t] + k0, bb + dofs[t]);
    }
  };

  floatx16 acc[4][2] = {};
  STAGE(0, 0);
  const int NK = K >> 6;
  for (int kt = 0; kt < NK; ++kt) {
    __syncthreads();  // drains stage(kt) [issued one full compute phase ago] + rendezvous
    if (kt + 1 < NK) STAGE((kt + 1) & 1, (kt + 1) << 6);  // prefetch; lands by next barrier
    const char* As_ = gsm + (kt & 1) * 65536;
    const char* Bs_ = As_ + 32768;
#pragma unroll
    for (int ks = 0; ks < 4; ++ks) {
      bf16x8 af[4], bfr[2];
#pragma unroll
      for (int mi = 0; mi < 4; ++mi) {
        const int r = wm * 128 + mi * 32 + l31;
        af[mi] = *(const bf16x8*)(As_ + r * 128 + (((ks * 2 + l5) ^ (r & 7)) << 4));
      }
#pragma unroll
      for (int ni = 0; ni < 2; ++ni) {
        const int r = wn * 64 + ni * 32 + l31;
        bfr[ni] = *(const bf16x8*)(Bs_ + r * 128 + (((ks * 2 + l5) ^ (r & 7)) << 4));
      }
      __builtin_amdgcn_s_setprio(1);
#pragma unroll
      for (int mi = 0; mi < 4; ++mi)
#pragma unroll
        for (int ni = 0; ni < 2; ++ni)
          acc[mi][ni] = __builtin_amdgcn_mfma_f32_32x32x16_bf16(af[mi], bfr[ni], acc[mi][ni], 0, 0, 0);
      __builtin_amdgcn_s_setprio(0);
    }
  }
  // Epilogue: 32x32 C/D layout col=l&31, row=(reg&3)+8*(reg>>2)+4*(l>>5) [m74/m101]
  const int crow0 = m0 + wm * 128 + 4 * l5;
  const int ccol = n0 + wn * 64 + l31;
#pragma unroll
  for (int mi = 0; mi < 4; ++mi)
#pragma unroll
    for (int ni = 0; ni < 2; ++ni)
#pragma unroll
      for (int reg = 0; reg < 16; ++reg) {
        const int row = crow0 + mi * 32 + (reg & 3) + 8 * (reg >> 2);
        C[(long)row * N + ccol + ni * 32] = (OUT_T)acc[mi][ni][reg];
      }
}

// ---------------- depthwise causal conv + SiLU + l2norm -> q,k,v (vectorized) ---------
__global__ __launch_bounds__(256) void k_conv(const bf16_t* __restrict__ qkvz,
                                              const float* __restrict__ conv_w,
                                              bf16_t* __restrict__ q, bf16_t* __restrict__ k,
                                              bf16_t* __restrict__ v) {
  int row = blockIdx.x;  // b*T + t
  int b = row >> 11, t = row & 2047;
  __shared__ float ys[6144];
  __shared__ float gsum[32][9];
  __shared__ float norms[32];
  const int c0 = threadIdx.x * 8;
  for (int c8 = c0; c8 < 6144; c8 += 2048) {
    bf16x8 xr[4];
#pragma unroll
    for (int w2 = 0; w2 < 4; ++w2) {
      int tt = t - 3 + w2;
      bf16x8 zr = {};
      xr[w2] = (tt >= 0) ? *(const bf16x8*)&qkvz[((long)(b * 2048 + tt)) * 8192 + c8] : zr;
    }
#pragma unroll
    for (int j = 0; j < 8; ++j) {
      float4 wv = *(const float4*)&conv_w[(c8 + j) * 4];
      float a = (float)xr[0][j] * wv.x + (float)xr[1][j] * wv.y +
                (float)xr[2][j] * wv.z + (float)xr[3][j] * wv.w;
      ys[c8 + j] = a / (1.f + __expf(-a));  // silu
    }
  }
  __syncthreads();
  {
    int g = threadIdx.x >> 3, j = threadIdx.x & 7;
    float s = 0.f;
#pragma unroll
    for (int e = 0; e < 16; ++e) {
      float yv = ys[g * 128 + j * 16 + e];
      s += yv * yv;
    }
    gsum[g][j] = s;
  }
  __syncthreads();
  if (threadIdx.x < 32) {
    float s = 0.f;
#pragma unroll
    for (int j = 0; j < 8; j++) s += gsum[threadIdx.x][j];
    norms[threadIdx.x] = 1.f / fmaxf(sqrtf(s), 1e-12f);
  }
  __syncthreads();
  for (int c8 = c0; c8 < 6144; c8 += 2048) {
    float scale;
    bf16_t* dst;
    if (c8 < 2048) {
      int h = c8 >> 7;
      scale = norms[h];
      dst = q + (((long)(b * 16 + h)) * 2048 + t) * 128 + (c8 & 127);
    } else if (c8 < 4096) {
      int h = (c8 - 2048) >> 7;
      scale = norms[16 + h];
      dst = k + (((long)(b * 16 + h)) * 2048 + t) * 128 + (c8 & 127);
    } else {
      scale = 1.f;
      int h = (c8 - 4096) >> 7;
      dst = v + (((long)(b * 16 + h)) * 2048 + t) * 128 + (c8 & 127);
    }
    bf16x8 o;
#pragma unroll
    for (int j = 0; j < 8; ++j) o[j] = (bf16_t)(ys[c8 + j] * scale);
    *(bf16x8*)dst = o;
  }
}

// ---------------- k,v natural -> kT,vT stripes inside dead qkvz region ----------------
// kT element (bh,dk,t) at qkvz elem (bh*128+dk)*8192 + 2048 + t
// vT element (bh,dv,t) at qkvz elem (bh*128+dv)*8192 + 4096 + t
__global__ __launch_bounds__(256) void k_tr_kv(const bf16_t* __restrict__ kv,
                                               const bf16_t* __restrict__ vv,
                                               bf16_t* __restrict__ qkvz) {
  __shared__ bf16_t t_lds[64 * 136];
  int bh = blockIdx.x >> 5, tc = blockIdx.x & 31;
  int t0 = tc * 64;
  int tid = threadIdx.x;
#pragma unroll
  for (int pass = 0; pass < 2; ++pass) {
    const bf16_t* src = (pass == 0 ? kv : vv) + (long)bh * 2048 * 128 + (long)t0 * 128;
    int r = tid >> 2, sc = (tid & 3) * 32;
    bf16x8 x0 = *(const bf16x8*)(src + (long)r * 128 + sc);
    bf16x8 x1 = *(const bf16x8*)(src + (long)r * 128 + sc + 8);
    bf16x8 x2 = *(const bf16x8*)(src + (long)r * 128 + sc + 16);
    bf16x8 x3 = *(const bf16x8*)(src + (long)r * 128 + sc + 24);
    __syncthreads();
    *(bf16x8*)&t_lds[r * 136 + sc] = x0;
    *(bf16x8*)&t_lds[r * 136 + sc + 8] = x1;
    *(bf16x8*)&t_lds[r * 136 + sc + 16] = x2;
    *(bf16x8*)&t_lds[r * 136 + sc + 24] = x3;
    __syncthreads();
    int d = tid >> 1, h2 = tid & 1;
    bf16_t* dst = qkvz + (long)(bh * 128 + d) * 8192 + (pass ? 4096 : 2048) + t0 + h2 * 32;
#pragma unroll
    for (int g = 0; g < 4; ++g) {
      bf16x8 o;
#pragma unroll
      for (int j = 0; j < 8; ++j) o[j] = t_lds[(h2 * 32 + g * 8 + j) * 136 + d];
      *(bf16x8*)(dst + g * 8) = o;
    }
  }
}

// ---------------- fused chunked gated-linear-attention scan (dv-split 4-way) ----------
__global__ __launch_bounds__(512, 1) void k_scan_chunked(
    const bf16_t* __restrict__ qv, const bf16_t* __restrict__ kv,
    bf16_t* __restrict__ qkvz, float* __restrict__ so_hi,
    const float* __restrict__ beta, const float* __restrict__ alpha) {
  extern __shared__ char smem[];
  bf16_t* q_lds = (bf16_t*)smem;            // [64][136] = 17408 B
  bf16_t* kn_lds = q_lds + 8704;            // [64][136]
  bf16_t* kT_lds = kn_lds + 8704;           // [128][72] = 18432 B
  bf16_t* vT_lds = kT_lds + 9216;           // [32][72]  = 4608 B
  bf16_t* P_lds = vT_lds + 2304;            // [64][72]  = 9216 B
  bf16_t* St_lds = P_lds + 4608;            // [32][136] = 8704 B
  float* G_lds = (float*)(St_lds + 4352);   // [64]
  float* bet_lds = G_lds + 64;
  float* w_lds = bet_lds + 64;              // beta_s * exp(Gend - G_s)
  float* eG_lds = w_lds + 64;               // exp(G_t)

  const int bh = blockIdx.x, dvb = blockIdx.y;
  const int b = bh >> 4, h = bh & 15;
  const int tid = threadIdx.x;
  const int w = tid >> 6, l = tid & 63;
  const int l15 = l & 15, lg = l >> 4;
  const int g = w & 1, r = w >> 1;

  const bf16_t* qb = qv + (long)bh * 2048 * 128;
  const bf16_t* kb = kv + (long)bh * 2048 * 128;
  const bf16_t* kTg = qkvz + (long)bh * 128 * 8192 + 2048;
  const bf16_t* vTg = qkvz + (long)(bh * 128 + dvb * 32) * 8192 + 4096;
  const float* bet = beta + (long)bh * 2048;
  const float* alp = alpha + (long)bh * 2048;

  floatx4 streg[2] = {};
  for (int i = tid; i < 2176; i += 512) ((float*)St_lds)[i] = 0.f;
  __syncthreads();

  const int sr = tid >> 3, ssc = (tid & 7) * 16;    // q/kn: 64 x 128
  const int sdk = tid >> 2, ssc2 = (tid & 3) * 16;  // kT: 128 x 64

  for (int c = 0; c < 32; ++c) {
    const int t0 = c * 64;
    // ---- phase A: stage tiles + (wave0) decay math ----
    {
      const bf16_t* qs = qb + (long)(t0 + sr) * 128 + ssc;
      const bf16_t* ks = kb + (long)(t0 + sr) * 128 + ssc;
      const bf16_t* kts = kTg + (long)sdk * 8192 + t0 + ssc2;
      bf16x8 a0 = *(const bf16x8*)qs, a1 = *(const bf16x8*)(qs + 8);
      bf16x8 b0 = *(const bf16x8*)ks, b1 = *(const bf16x8*)(ks + 8);
      bf16x8 c0 = *(const bf16x8*)kts, c1 = *(const bf16x8*)(kts + 8);
      *(bf16x8*)&q_lds[sr * 136 + ssc] = a0;
      *(bf16x8*)&q_lds[sr * 136 + ssc + 8] = a1;
      *(bf16x8*)&kn_lds[sr * 136 + ssc] = b0;
      *(bf16x8*)&kn_lds[sr * 136 + ssc + 8] = b1;
      *(bf16x8*)&kT_lds[sdk * 72 + ssc2] = c0;
      *(bf16x8*)&kT_lds[sdk * 72 + ssc2 + 8] = c1;
      if (tid < 256) {
        int svr = tid >> 3, svc = (tid & 7) * 8;
        bf16x8 d0 = *(const bf16x8*)(vTg + (long)svr * 8192 + t0 + svc);
        *(bf16x8*)&vT_lds[svr * 72 + svc] = d0;
      }
      if (w == 0) {
        float bsv = bet[t0 + l];
        float la = __logf(alp[t0 + l]);
#pragma unroll
        for (int off = 1; off < 64; off <<= 1) {
          float xup = __shfl_up(la, off);
          if (l >= off) la += xup;
        }
        float ge = __shfl(la, 63);
        G_lds[l] = la;
        bet_lds[l] = bsv;
        w_lds[l] = bsv * __expf(ge - la);
        eG_lds[l] = __expf(la);
      }
    }
    __syncthreads();  // b1

    // ---- phase B: scale kT in place ----
    {
      bf16_t* p = &kT_lds[sdk * 72 + ssc2];
      bf16x8 x0 = *(bf16x8*)p, x1 = *(bf16x8*)(p + 8);
#pragma unroll
      for (int j = 0; j < 8; j++) {
        x0[j] = (bf16_t)((float)x0[j] * w_lds[ssc2 + j]);
        x1[j] = (bf16_t)((float)x1[j] * w_lds[ssc2 + 8 + j]);
      }
      *(bf16x8*)p = x0;
      *(bf16x8*)(p + 8) = x1;
    }

    // ---- phase CD: score = q K^T (2 tiles/wave), build P ----
    {
      const int mi = w >> 1;
      bf16x8 aq[4];
#pragma unroll
      for (int ks = 0; ks < 4; ks++)
        aq[ks] = *(bf16x8*)&q_lds[(mi * 16 + l15) * 136 + ks * 32 + lg * 8];
#pragma unroll
      for (int sn2 = 0; sn2 < 2; sn2++) {
        const int sn = (w & 1) * 2 + sn2;
        floatx4 sc_ = {0.f, 0.f, 0.f, 0.f};
#pragma unroll
        for (int ks = 0; ks < 4; ks++) {
          bf16x8 bk = *(bf16x8*)&kn_lds[(sn * 16 + l15) * 136 + ks * 32 + lg * 8];
          sc_ = __builtin_amdgcn_mfma_f32_16x16x32_bf16(aq[ks], bk, sc_, 0, 0, 0);
        }
        const int sl = sn * 16 + l15;
        const float gs = G_lds[sl], bs = bet_lds[sl];
#pragma unroll
        for (int rr = 0; rr < 4; rr++) {
          const int tl = mi * 16 + lg * 4 + rr;
          float val = (sl <= tl) ? sc_[rr] * __expf(G_lds[tl] - gs) * bs : 0.f;
          P_lds[tl * 72 + sl] = (bf16_t)val;
        }
      }
    }
    __syncthreads();  // b3

    // ---- phase E: out(mi=r) = exp(Gt)*(q@S_in) + P@V ; state update (ni2 = 2r,2r+1) ----
    floatx4 acco = {0.f, 0.f, 0.f, 0.f};
    {
      const int rloc = g * 16 + l15;  // local dv row (block quarter)
      bf16x8 av0 = *(bf16x8*)&vT_lds[rloc * 72 + lg * 8];
      bf16x8 av1 = *(bf16x8*)&vT_lds[rloc * 72 + 32 + lg * 8];
      floatx4 f = {0.f, 0.f, 0.f, 0.f};
#pragma unroll
      for (int ks = 0; ks < 4; ks++) {
        bf16x8 aq = *(bf16x8*)&q_lds[(r * 16 + l15) * 136 + ks * 32 + lg * 8];
        bf16x8 bs_ = *(bf16x8*)&St_lds[rloc * 136 + ks * 32 + lg * 8];
        f = __builtin_amdgcn_mfma_f32_16x16x32_bf16(aq, bs_, f, 0, 0, 0);
      }
#pragma unroll
      for (int rr = 0; rr < 4; rr++) f[rr] *= eG_lds[r * 16 + lg * 4 + rr];
#pragma unroll
      for (int ks2 = 0; ks2 < 2; ks2++) {
        bf16x8 ap = *(bf16x8*)&P_lds[(r * 16 + l15) * 72 + ks2 * 32 + lg * 8];
        f = __builtin_amdgcn_mfma_f32_16x16x32_bf16(ap, (ks2 == 0) ? av0 : av1, f, 0, 0, 0);
      }
      acco = f;
      const float dcv = eG_lds[63];
#pragma unroll
      for (int ni = 0; ni < 2; ni++) {
        const int ni2 = r * 2 + ni;
#pragma unroll
        for (int rr = 0; rr < 4; rr++) streg[ni][rr] *= dcv;
        bf16x8 bk0 = *(bf16x8*)&kT_lds[(ni2 * 16 + l15) * 72 + lg * 8];
        bf16x8 bk1 = *(bf16x8*)&kT_lds[(ni2 * 16 + l15) * 72 + 32 + lg * 8];
        streg[ni] = __builtin_amdgcn_mfma_f32_16x16x32_bf16(av0, bk0, streg[ni], 0, 0, 0);
        streg[ni] = __builtin_amdgcn_mfma_f32_16x16x32_bf16(av1, bk1, streg[ni], 0, 0, 0);
      }
    }
    __syncthreads();  // b4

    // ---- phase F: publish new state + so write ----
#pragma unroll
    for (int ni = 0; ni < 2; ni++) {
      const int ni2 = r * 2 + ni;
#pragma unroll
      for (int rr = 0; rr < 4; rr++)
        St_lds[(g * 16 + lg * 4 + rr) * 136 + ni2 * 16 + l15] = (bf16_t)streg[ni][rr];
    }
    {
      const int dvg = dvb * 32 + g * 16 + l15;
      const int hcol = h * 128 + dvg;  // 0..2047
#pragma unroll
      for (int rr = 0; rr < 4; rr++) {
        const int t = t0 + r * 16 + lg * 4 + rr;
        const long row = (long)b * 2048 + t;
        if (hcol < 1024)
          ((float*)qkvz)[row * 4096 + hcol] = acco[rr];
        else
          so_hi[row * 1024 + hcol - 1024] = acco[rr];
      }
    }
  }
}

// ---------------- RMS norm + gate(z) -> A2 (contiguous, in dead qv buffer) -----------
__global__ __launch_bounds__(256) void k_rmsgate(const float* __restrict__ so_hi,
                                                 const bf16_t* __restrict__ qkvz,
                                                 bf16_t* __restrict__ A2,
                                                 const float* __restrict__ norm_w) {
  long row = blockIdx.x;  // b*T + t
  int tid = threadIdx.x;
  int h = tid >> 4, j = tid & 15;
  const float* srow = (h < 8) ? (const float*)qkvz + row * 4096 + h * 128 + j * 8
                              : so_hi + row * 1024 + (h - 8) * 128 + j * 8;
  float xv[8];
  *(float4*)&xv[0] = *(const float4*)srow;
  *(float4*)&xv[4] = *(const float4*)(srow + 4);
  float ss = 0.f;
#pragma unroll
  for (int e = 0; e < 8; e++) ss += xv[e] * xv[e];
  ss += __shfl_xor(ss, 1); ss += __shfl_xor(ss, 2);
  ss += __shfl_xor(ss, 4); ss += __shfl_xor(ss, 8);
  float rinv = rsqrtf(ss * (1.0f / 128.0f) + 1e-6f);
  const bf16_t* zrow = qkvz + row * 8192 + 6144 + h * 128 + j * 8;
  bf16x8 zv = *(const bf16x8*)zrow;
  bf16x8 o;
#pragma unroll
  for (int e = 0; e < 8; e++) {
    float z = (float)zv[e];
    float gate = 1.f / (1.f + __expf(-z));
    o[e] = (bf16_t)(xv[e] * rinv * norm_w[j * 8 + e] * gate);
  }
  *(bf16x8*)(A2 + row * 2048 + h * 128 + j * 8) = o;
}

extern "C" void kernel_launch(void* const* d_in, const int* in_sizes, int n_in,
                              void* d_out, int out_size, void* d_ws, size_t ws_size,
                              hipStream_t stream) {
  const float* x      = (const float*)d_in[0];
  // d_in[1] = positions (unused)
  const float* W_qkvz = (const float*)d_in[2];
  const float* W_b    = (const float*)d_in[3];
  const float* W_a    = (const float*)d_in[4];
  const float* conv_w = (const float*)d_in[5];
  const float* norm_w = (const float*)d_in[6];
  const float* W_out  = (const float*)d_in[7];
  float* out = (float*)d_out;
  char* ws = (char*)d_ws;

  // Workspace layout (244,580,352 bytes). qkvz row (16 KB) lifecycle:
  //  [0,4K): qkv cols (dead post-conv) -> so_lo fp32[1024] (scan -> rmsgate)
  //  [4K,8K): kT stripe (tr_kv -> scan)
  //  [8K,12K): vT stripe (tr_kv -> scan)
  //  [12K,16K): z (gemm1 -> rmsgate)
  // xb/qv region: xb (cast -> gemm1), qv (conv -> scan), A2 contiguous (rmsgate -> gemm2).
  // vv: v natural (conv -> tr_kv) -> so_hi fp32 (scan -> rmsgate).
  bf16_t* qkvz  = (bf16_t*)(ws + 0);
  bf16_t* xb    = (bf16_t*)(ws + 134217728);
  bf16_t* qv    = (bf16_t*)(ws + 134217728);   // aliases xb
  bf16_t* A2    = (bf16_t*)(ws + 134217728);   // aliases qv (dead after scan)
  bf16_t* WqT   = (bf16_t*)(ws + 167772160);
  bf16_t* kv    = (bf16_t*)(ws + 167772160);   // aliases WqT
  bf16_t* vv    = (bf16_t*)(ws + 201326592);
  float*  so_hi = (float*)(ws + 201326592);    // aliases vv
  bf16_t* WoT   = (bf16_t*)(ws + 234881024);
  float*  WbT   = (float*)(ws + 243269632);
  float*  WaT   = (float*)(ws + 243400704);
  float*  beta  = (float*)(ws + 243531776);
  float*  alpha = (float*)(ws + 244056064);

  if (ws_size < 244580352) return;

  k_cast_bf16<<<8192, 256, 0, stream>>>(x, xb);
  k_transpose_cast<<<dim3(8192 / 32, 2048 / 32), dim3(32, 8), 0, stream>>>(W_qkvz, WqT, 2048, 8192);
  k_transpose_cast<<<dim3(2048 / 32, 2048 / 32), dim3(32, 8), 0, stream>>>(W_out, WoT, 2048, 2048);
  k_transpose_f32<<<8, 256, 0, stream>>>(W_b, WbT, 2048, 16);
  k_transpose_f32<<<8, 256, 0, stream>>>(W_a, WaT, 2048, 16);
  k_beta_alpha<<<512, 256, 131072, stream>>>(x, WbT, WaT, beta, alpha);
  k_gemm256<bf16_t><<<dim3(32, 32), 512, 131072, stream>>>(xb, WqT, qkvz, 8192, 2048, 2048);
  k_conv<<<8192, 256, 0, stream>>>(qkvz, conv_w, qv, kv, vv);
  k_tr_kv<<<2048, 256, 0, stream>>>(kv, vv, qkvz);
  k_scan_chunked<<<dim3(64, 4), 512, 76800, stream>>>(qv, kv, qkvz, so_hi, beta, alpha);
  k_rmsgate<<<8192, 256, 0, stream>>>(so_hi, qkvz, A2, norm_w);
  k_gemm256<float><<<dim3(8, 32), 512, 131072, stream>>>(A2, WoT, out, 2048, 2048, 2048);
  (void)in_sizes; (void)n_in; (void)out_size;
}

// Round 10
// 821.787 us; speedup vs baseline: 1.0632x; 1.0632x over previous
//
#include <hip/hip_runtime.h>
#include <hip/hip_bf16.h>

typedef __bf16 bf16_t;
typedef __attribute__((ext_vector_type(8))) __bf16 bf16x8;
typedef __attribute__((ext_vector_type(4))) float floatx4;

// Problem constants: B=4, T=2048, C=2048, H=16, D=128, QKV_DIM=6144, QKVZ=8192, BT=8192

__device__ __forceinline__ void gload16(const void* g, void* l) {
  __builtin_amdgcn_global_load_lds(
      (const __attribute__((address_space(1))) void*)g,
      (__attribute__((address_space(3))) void*)l, 16, 0, 0);
}

// ---------------- cast fp32 -> bf16 (vectorized) ----------------
__global__ __launch_bounds__(256) void k_cast_bf16(const float* __restrict__ in,
                                                   bf16_t* __restrict__ out) {
  long i = ((long)blockIdx.x * 256 + threadIdx.x) * 8;
  const float4 a = *(const float4*)(in + i);
  const float4 b = *(const float4*)(in + i + 4);
  bf16x8 o;
  o[0] = (bf16_t)a.x; o[1] = (bf16_t)a.y; o[2] = (bf16_t)a.z; o[3] = (bf16_t)a.w;
  o[4] = (bf16_t)b.x; o[5] = (bf16_t)b.y; o[6] = (bf16_t)b.z; o[7] = (bf16_t)b.w;
  *(bf16x8*)(out + i) = o;
}

// ---------------- transpose + cast fp32 -> bf16 ----------------
__global__ void k_transpose_cast(const float* __restrict__ in, bf16_t* __restrict__ out,
                                 int R, int Ccols) {
  __shared__ float tile[32][33];
  int c0 = blockIdx.x * 32, r0 = blockIdx.y * 32;
  for (int i = threadIdx.y; i < 32; i += 8)
    tile[i][threadIdx.x] = in[(long)(r0 + i) * Ccols + c0 + threadIdx.x];
  __syncthreads();
  for (int i = threadIdx.y; i < 32; i += 8)
    out[(long)(c0 + i) * R + r0 + threadIdx.x] = (bf16_t)tile[threadIdx.x][i];
}

// small fp32 transpose (for W_b / W_a: 2048x16 -> 16x2048)
__global__ void k_transpose_f32(const float* __restrict__ in, float* __restrict__ out,
                                int R, int Ccols) {
  int r = blockIdx.x * blockDim.x + threadIdx.x;
  if (r < R)
    for (int c = 0; c < Ccols; ++c) out[(long)c * R + r] = in[(long)r * Ccols + c];
}

// ---------------- beta/alpha v2: sigmoid(x @ W), 16 rows/block, x in LDS -------------
__global__ __launch_bounds__(256) void k_beta_alpha(const float* __restrict__ x,
                                                    const float* __restrict__ WbT,
                                                    const float* __restrict__ WaT,
                                                    float* __restrict__ beta,
                                                    float* __restrict__ alpha) {
  extern __shared__ float xs[];  // [16][2048]
  const long row0 = (long)blockIdx.x * 16;
  const int tid = threadIdx.x;
  {
    const float4* src = (const float4*)(x + row0 * 2048);
    float4* dst = (float4*)xs;
    for (int i = tid; i < 16 * 512; i += 256) dst[i] = src[i];
  }
  __syncthreads();
  const int wv = tid >> 6, lane = tid & 63;
  for (int oo = 0; oo < 8; ++oo) {
    const int o = wv * 8 + oo;
    const float* Wrow = (o < 16) ? (WbT + (long)o * 2048) : (WaT + (long)(o - 16) * 2048);
    float acc[16];
#pragma unroll
    for (int r = 0; r < 16; ++r) acc[r] = 0.f;
    for (int kc = 0; kc < 8; ++kc) {
      const float4 w4 = *(const float4*)(Wrow + kc * 256 + lane * 4);
#pragma unroll
      for (int r = 0; r < 16; ++r) {
        const float4 xv = *(const float4*)&xs[r * 2048 + kc * 256 + lane * 4];
        acc[r] += w4.x * xv.x + w4.y * xv.y + w4.z * xv.z + w4.w * xv.w;
      }
    }
#pragma unroll
    for (int r = 0; r < 16; ++r) {
      float s = acc[r];
      for (int off = 32; off; off >>= 1) s += __shfl_down(s, off);
      if (lane == 0) {
        const long row = row0 + r;
        const int b = (int)(row >> 11), t = (int)(row & 2047);
        const float sig = 1.f / (1.f + __expf(-s));
        float* dst = (o < 16) ? beta : alpha;
        dst[((long)(b * 16 + (o & 15))) * 2048 + t] = sig;
      }
    }
  }
}

// ---------------- bf16 MFMA GEMM 256x256 (16x16x32 frags): C = A @ Bt^T --------------
// Round-8 proven version: BM=BN=256, BK=64, 512 threads = 8 waves (2M x 4N), per-wave
// 128x64 = acc[8][4]. LDS double-buffered 128 KiB. T2 swizzle: chunk (row,c) at
// (row, c ^ (row&7)); linear gload dest + inverse-permuted global source; reads XOR.
// Per-quarter-wave reads: 8 chunks x 2-way -> conflict-free (measured 0).
// Pipeline: ONE barrier per K-step; STAGE(kt+1 -> other buffer) issued right after the
// barrier, drained by the NEXT barrier => drain covered by a full 64-MFMA compute phase.
template <typename OUT_T>
__global__ __launch_bounds__(512, 2) void k_gemm256(const bf16_t* __restrict__ A,
                                                    const bf16_t* __restrict__ Bt,
                                                    OUT_T* __restrict__ C,
                                                    int N, int K, int lda) {
  extern __shared__ char gsm[];  // [buf0: A 32K | B 32K][buf1: A 32K | B 32K]
  const int m0 = blockIdx.y * 256, n0 = blockIdx.x * 256;
  const int tid = threadIdx.x;
  const int w = tid >> 6, l = tid & 63;
  const int wm = w >> 2, wn = w & 3;
  const int l15 = l & 15, lg = l >> 4;

  const bf16_t* asrc[4];
  const bf16_t* bsrc[4];
  int dofs[4];
#pragma unroll
  for (int t = 0; t < 4; ++t) {
    int c = t * 512 + tid;
    int row = c >> 3, cs = (c & 7) ^ (row & 7);  // pre-swizzled source chunk
    asrc[t] = A + (long)(m0 + row) * lda + cs * 8;
    bsrc[t] = Bt + (long)(n0 + row) * K + cs * 8;
    dofs[t] = c * 16;
  }

  auto STAGE = [&](int buf, int k0) {
    char* ab = gsm + buf * 65536;
    char* bb = ab + 32768;
#pragma unroll
    for (int t = 0; t < 4; ++t) {
      gload16(asrc[t] + k0, ab + dofs[t]);
      gload16(bsrc[t] + k0, bb + dofs[t]);
    }
  };

  floatx4 acc[8][4] = {};
  STAGE(0, 0);
  const int NK = K >> 6;
  for (int kt = 0; kt < NK; ++kt) {
    __syncthreads();  // drains stage(kt) [issued one full compute phase ago] + rendezvous
    if (kt + 1 < NK) STAGE((kt + 1) & 1, (kt + 1) << 6);  // prefetch; lands by next barrier
    const char* As_ = gsm + (kt & 1) * 65536;
    const char* Bs_ = As_ + 32768;
#pragma unroll
    for (int ks = 0; ks < 2; ++ks) {
      bf16x8 af[8], bfr[4];
#pragma unroll
      for (int mi = 0; mi < 8; ++mi) {
        const int r = wm * 128 + mi * 16 + l15;
        af[mi] = *(const bf16x8*)(As_ + r * 128 + ((((ks << 2) + lg) ^ (r & 7)) << 4));
      }
#pragma unroll
      for (int ni = 0; ni < 4; ++ni) {
        const int r = wn * 64 + ni * 16 + l15;
        bfr[ni] = *(const bf16x8*)(Bs_ + r * 128 + ((((ks << 2) + lg) ^ (r & 7)) << 4));
      }
      __builtin_amdgcn_s_setprio(1);
#pragma unroll
      for (int mi = 0; mi < 8; ++mi)
#pragma unroll
        for (int ni = 0; ni < 4; ++ni)
          acc[mi][ni] = __builtin_amdgcn_mfma_f32_16x16x32_bf16(af[mi], bfr[ni], acc[mi][ni], 0, 0, 0);
      __builtin_amdgcn_s_setprio(0);
    }
  }
  // Epilogue: C/D layout row=(l>>4)*4+r, col=l&15 [m89-verified]
  const int crow0 = m0 + wm * 128 + lg * 4;
  const int ccol = n0 + wn * 64 + l15;
#pragma unroll
  for (int mi = 0; mi < 8; ++mi)
#pragma unroll
    for (int ni = 0; ni < 4; ++ni)
#pragma unroll
      for (int r = 0; r < 4; ++r)
        C[(long)(crow0 + mi * 16 + r) * N + ccol + ni * 16] = (OUT_T)acc[mi][ni][r];
}

// ---------------- depthwise causal conv + SiLU + l2norm -> q,k,v (vectorized) ---------
__global__ __launch_bounds__(256) void k_conv(const bf16_t* __restrict__ qkvz,
                                              const float* __restrict__ conv_w,
                                              bf16_t* __restrict__ q, bf16_t* __restrict__ k,
                                              bf16_t* __restrict__ v) {
  int row = blockIdx.x;  // b*T + t
  int b = row >> 11, t = row & 2047;
  __shared__ float ys[6144];
  __shared__ float gsum[32][9];
  __shared__ float norms[32];
  const int c0 = threadIdx.x * 8;
  for (int c8 = c0; c8 < 6144; c8 += 2048) {
    bf16x8 xr[4];
#pragma unroll
    for (int w2 = 0; w2 < 4; ++w2) {
      int tt = t - 3 + w2;
      bf16x8 zr = {};
      xr[w2] = (tt >= 0) ? *(const bf16x8*)&qkvz[((long)(b * 2048 + tt)) * 8192 + c8] : zr;
    }
#pragma unroll
    for (int j = 0; j < 8; ++j) {
      float4 wv = *(const float4*)&conv_w[(c8 + j) * 4];
      float a = (float)xr[0][j] * wv.x + (float)xr[1][j] * wv.y +
                (float)xr[2][j] * wv.z + (float)xr[3][j] * wv.w;
      ys[c8 + j] = a / (1.f + __expf(-a));  // silu
    }
  }
  __syncthreads();
  {
    int g = threadIdx.x >> 3, j = threadIdx.x & 7;
    float s = 0.f;
#pragma unroll
    for (int e = 0; e < 16; ++e) {
      float yv = ys[g * 128 + j * 16 + e];
      s += yv * yv;
    }
    gsum[g][j] = s;
  }
  __syncthreads();
  if (threadIdx.x < 32) {
    float s = 0.f;
#pragma unroll
    for (int j = 0; j < 8; j++) s += gsum[threadIdx.x][j];
    norms[threadIdx.x] = 1.f / fmaxf(sqrtf(s), 1e-12f);
  }
  __syncthreads();
  for (int c8 = c0; c8 < 6144; c8 += 2048) {
    float scale;
    bf16_t* dst;
    if (c8 < 2048) {
      int h = c8 >> 7;
      scale = norms[h];
      dst = q + (((long)(b * 16 + h)) * 2048 + t) * 128 + (c8 & 127);
    } else if (c8 < 4096) {
      int h = (c8 - 2048) >> 7;
      scale = norms[16 + h];
      dst = k + (((long)(b * 16 + h)) * 2048 + t) * 128 + (c8 & 127);
    } else {
      scale = 1.f;
      int h = (c8 - 4096) >> 7;
      dst = v + (((long)(b * 16 + h)) * 2048 + t) * 128 + (c8 & 127);
    }
    bf16x8 o;
#pragma unroll
    for (int j = 0; j < 8; ++j) o[j] = (bf16_t)(ys[c8 + j] * scale);
    *(bf16x8*)dst = o;
  }
}

// ---------------- k,v natural -> kT,vT stripes inside dead qkvz region ----------------
__global__ __launch_bounds__(256) void k_tr_kv(const bf16_t* __restrict__ kv,
                                               const bf16_t* __restrict__ vv,
                                               bf16_t* __restrict__ qkvz) {
  __shared__ bf16_t t_lds[64 * 136];
  int bh = blockIdx.x >> 5, tc = blockIdx.x & 31;
  int t0 = tc * 64;
  int tid = threadIdx.x;
#pragma unroll
  for (int pass = 0; pass < 2; ++pass) {
    const bf16_t* src = (pass == 0 ? kv : vv) + (long)bh * 2048 * 128 + (long)t0 * 128;
    int r = tid >> 2, sc = (tid & 3) * 32;
    bf16x8 x0 = *(const bf16x8*)(src + (long)r * 128 + sc);
    bf16x8 x1 = *(const bf16x8*)(src + (long)r * 128 + sc + 8);
    bf16x8 x2 = *(const bf16x8*)(src + (long)r * 128 + sc + 16);
    bf16x8 x3 = *(const bf16x8*)(src + (long)r * 128 + sc + 24);
    __syncthreads();
    *(bf16x8*)&t_lds[r * 136 + sc] = x0;
    *(bf16x8*)&t_lds[r * 136 + sc + 8] = x1;
    *(bf16x8*)&t_lds[r * 136 + sc + 16] = x2;
    *(bf16x8*)&t_lds[r * 136 + sc + 24] = x3;
    __syncthreads();
    int d = tid >> 1, h2 = tid & 1;
    bf16_t* dst = qkvz + (long)(bh * 128 + d) * 8192 + (pass ? 4096 : 2048) + t0 + h2 * 32;
#pragma unroll
    for (int g = 0; g < 4; ++g) {
      bf16x8 o;
#pragma unroll
      for (int j = 0; j < 8; ++j) o[j] = t_lds[(h2 * 32 + g * 8 + j) * 136 + d];
      *(bf16x8*)(dst + g * 8) = o;
    }
  }
}

// ---------------- fused chunked gated-linear-attention scan (dv-split 4-way) ----------
// Grid (64 bh, 4 dvb), 512 threads = 8 waves. T14 async-stage: each chunk's global
// loads are issued right after the PREVIOUS chunk's b1 barrier into registers, hiding
// HBM/L2 latency under that chunk's QK^T/PV/state compute.
__global__ __launch_bounds__(512, 1) void k_scan_chunked(
    const bf16_t* __restrict__ qv, const bf16_t* __restrict__ kv,
    bf16_t* __restrict__ qkvz, float* __restrict__ so_hi,
    const float* __restrict__ beta, const float* __restrict__ alpha) {
  extern __shared__ char smem[];
  bf16_t* q_lds = (bf16_t*)smem;            // [64][136] = 17408 B
  bf16_t* kn_lds = q_lds + 8704;            // [64][136]
  bf16_t* kT_lds = kn_lds + 8704;           // [128][72] = 18432 B
  bf16_t* vT_lds = kT_lds + 9216;           // [32][72]  = 4608 B
  bf16_t* P_lds = vT_lds + 2304;            // [64][72]  = 9216 B
  bf16_t* St_lds = P_lds + 4608;            // [32][136] = 8704 B
  float* G_lds = (float*)(St_lds + 4352);   // [64]
  float* bet_lds = G_lds + 64;
  float* w_lds = bet_lds + 64;              // beta_s * exp(Gend - G_s)
  float* eG_lds = w_lds + 64;               // exp(G_t)

  const int bh = blockIdx.x, dvb = blockIdx.y;
  const int b = bh >> 4, h = bh & 15;
  const int tid = threadIdx.x;
  const int w = tid >> 6, l = tid & 63;
  const int l15 = l & 15, lg = l >> 4;
  const int g = w & 1, r = w >> 1;

  const bf16_t* qb = qv + (long)bh * 2048 * 128;
  const bf16_t* kb = kv + (long)bh * 2048 * 128;
  const bf16_t* kTg = qkvz + (long)bh * 128 * 8192 + 2048;
  const bf16_t* vTg = qkvz + (long)(bh * 128 + dvb * 32) * 8192 + 4096;
  const float* bet = beta + (long)bh * 2048;
  const float* alp = alpha + (long)bh * 2048;

  floatx4 streg[2] = {};
  for (int i = tid; i < 2176; i += 512) ((float*)St_lds)[i] = 0.f;
  __syncthreads();

  const int sr = tid >> 3, ssc = (tid & 7) * 16;    // q/kn: 64 x 128
  const int sdk = tid >> 2, ssc2 = (tid & 3) * 16;  // kT: 128 x 64
  const int svr = tid >> 3, svc = (tid & 7) * 8;    // vT: 32 x 64 (tid<256)

  // T14 prefetch registers (chunk 0)
  bf16x8 ra0, ra1, rb0, rb1, rc0, rc1, rd0 = {};
  float rbet = 0.f, ralp = 1.f;
  {
    const bf16_t* qs = qb + (long)sr * 128 + ssc;
    const bf16_t* ks = kb + (long)sr * 128 + ssc;
    const bf16_t* kts = kTg + (long)sdk * 8192 + ssc2;
    ra0 = *(const bf16x8*)qs; ra1 = *(const bf16x8*)(qs + 8);
    rb0 = *(const bf16x8*)ks; rb1 = *(const bf16x8*)(ks + 8);
    rc0 = *(const bf16x8*)kts; rc1 = *(const bf16x8*)(kts + 8);
    if (tid < 256) rd0 = *(const bf16x8*)(vTg + (long)svr * 8192 + svc);
    if (w == 0) { rbet = bet[l]; ralp = alp[l]; }
  }

  for (int c = 0; c < 32; ++c) {
    const int t0 = c * 64;
    // ---- phase A: write prefetched regs to LDS + (wave0) decay math ----
    {
      *(bf16x8*)&q_lds[sr * 136 + ssc] = ra0;
      *(bf16x8*)&q_lds[sr * 136 + ssc + 8] = ra1;
      *(bf16x8*)&kn_lds[sr * 136 + ssc] = rb0;
      *(bf16x8*)&kn_lds[sr * 136 + ssc + 8] = rb1;
      *(bf16x8*)&kT_lds[sdk * 72 + ssc2] = rc0;
      *(bf16x8*)&kT_lds[sdk * 72 + ssc2 + 8] = rc1;
      if (tid < 256) *(bf16x8*)&vT_lds[svr * 72 + svc] = rd0;
      if (w == 0) {
        float bsv = rbet;
        float la = __logf(ralp);
#pragma unroll
        for (int off = 1; off < 64; off <<= 1) {
          float xup = __shfl_up(la, off);
          if (l >= off) la += xup;
        }
        float ge = __shfl(la, 63);
        G_lds[l] = la;
        bet_lds[l] = bsv;
        w_lds[l] = bsv * __expf(ge - la);
        eG_lds[l] = __expf(la);
      }
    }
    __syncthreads();  // b1

    // ---- T14: issue next chunk's global loads (hide latency under compute) ----
    if (c + 1 < 32) {
      const int t1 = t0 + 64;
      const bf16_t* qs = qb + (long)(t1 + sr) * 128 + ssc;
      const bf16_t* ks = kb + (long)(t1 + sr) * 128 + ssc;
      const bf16_t* kts = kTg + (long)sdk * 8192 + t1 + ssc2;
      ra0 = *(const bf16x8*)qs; ra1 = *(const bf16x8*)(qs + 8);
      rb0 = *(const bf16x8*)ks; rb1 = *(const bf16x8*)(ks + 8);
      rc0 = *(const bf16x8*)kts; rc1 = *(const bf16x8*)(kts + 8);
      if (tid < 256) rd0 = *(const bf16x8*)(vTg + (long)svr * 8192 + t1 + svc);
      if (w == 0) { rbet = bet[t1 + l]; ralp = alp[t1 + l]; }
    }

    // ---- phase B: scale kT in place ----
    {
      bf16_t* p = &kT_lds[sdk * 72 + ssc2];
      bf16x8 x0 = *(bf16x8*)p, x1 = *(bf16x8*)(p + 8);
#pragma unroll
      for (int j = 0; j < 8; j++) {
        x0[j] = (bf16_t)((float)x0[j] * w_lds[ssc2 + j]);
        x1[j] = (bf16_t)((float)x1[j] * w_lds[ssc2 + 8 + j]);
      }
      *(bf16x8*)p = x0;
      *(bf16x8*)(p + 8) = x1;
    }

    // ---- phase CD: score = q K^T (2 tiles/wave), build P ----
    {
      const int mi = w >> 1;
      bf16x8 aq[4];
#pragma unroll
      for (int ks = 0; ks < 4; ks++)
        aq[ks] = *(bf16x8*)&q_lds[(mi * 16 + l15) * 136 + ks * 32 + lg * 8];
#pragma unroll
      for (int sn2 = 0; sn2 < 2; sn2++) {
        const int sn = (w & 1) * 2 + sn2;
        floatx4 sc_ = {0.f, 0.f, 0.f, 0.f};
#pragma unroll
        for (int ks = 0; ks < 4; ks++) {
          bf16x8 bk = *(bf16x8*)&kn_lds[(sn * 16 + l15) * 136 + ks * 32 + lg * 8];
          sc_ = __builtin_amdgcn_mfma_f32_16x16x32_bf16(aq[ks], bk, sc_, 0, 0, 0);
        }
        const int sl = sn * 16 + l15;
        const float gs = G_lds[sl], bs = bet_lds[sl];
#pragma unroll
        for (int rr = 0; rr < 4; rr++) {
          const int tl = mi * 16 + lg * 4 + rr;
          float val = (sl <= tl) ? sc_[rr] * __expf(G_lds[tl] - gs) * bs : 0.f;
          P_lds[tl * 72 + sl] = (bf16_t)val;
        }
      }
    }
    __syncthreads();  // b3

    // ---- phase E: out(mi=r) = exp(Gt)*(q@S_in) + P@V ; state update (ni2 = 2r,2r+1) ----
    floatx4 acco = {0.f, 0.f, 0.f, 0.f};
    {
      const int rloc = g * 16 + l15;  // local dv row (block quarter)
      bf16x8 av0 = *(bf16x8*)&vT_lds[rloc * 72 + lg * 8];
      bf16x8 av1 = *(bf16x8*)&vT_lds[rloc * 72 + 32 + lg * 8];
      floatx4 f = {0.f, 0.f, 0.f, 0.f};
#pragma unroll
      for (int ks = 0; ks < 4; ks++) {
        bf16x8 aq = *(bf16x8*)&q_lds[(r * 16 + l15) * 136 + ks * 32 + lg * 8];
        bf16x8 bs_ = *(bf16x8*)&St_lds[rloc * 136 + ks * 32 + lg * 8];
        f = __builtin_amdgcn_mfma_f32_16x16x32_bf16(aq, bs_, f, 0, 0, 0);
      }
#pragma unroll
      for (int rr = 0; rr < 4; rr++) f[rr] *= eG_lds[r * 16 + lg * 4 + rr];
#pragma unroll
      for (int ks2 = 0; ks2 < 2; ks2++) {
        bf16x8 ap = *(bf16x8*)&P_lds[(r * 16 + l15) * 72 + ks2 * 32 + lg * 8];
        f = __builtin_amdgcn_mfma_f32_16x16x32_bf16(ap, (ks2 == 0) ? av0 : av1, f, 0, 0, 0);
      }
      acco = f;
      const float dcv = eG_lds[63];
#pragma unroll
      for (int ni = 0; ni < 2; ni++) {
        const int ni2 = r * 2 + ni;
#pragma unroll
        for (int rr = 0; rr < 4; rr++) streg[ni][rr] *= dcv;
        bf16x8 bk0 = *(bf16x8*)&kT_lds[(ni2 * 16 + l15) * 72 + lg * 8];
        bf16x8 bk1 = *(bf16x8*)&kT_lds[(ni2 * 16 + l15) * 72 + 32 + lg * 8];
        streg[ni] = __builtin_amdgcn_mfma_f32_16x16x32_bf16(av0, bk0, streg[ni], 0, 0, 0);
        streg[ni] = __builtin_amdgcn_mfma_f32_16x16x32_bf16(av1, bk1, streg[ni], 0, 0, 0);
      }
    }
    __syncthreads();  // b4

    // ---- phase F: publish new state + so write ----
#pragma unroll
    for (int ni = 0; ni < 2; ni++) {
      const int ni2 = r * 2 + ni;
#pragma unroll
      for (int rr = 0; rr < 4; rr++)
        St_lds[(g * 16 + lg * 4 + rr) * 136 + ni2 * 16 + l15] = (bf16_t)streg[ni][rr];
    }
    {
      const int dvg = dvb * 32 + g * 16 + l15;
      const int hcol = h * 128 + dvg;  // 0..2047
#pragma unroll
      for (int rr = 0; rr < 4; rr++) {
        const int t = t0 + r * 16 + lg * 4 + rr;
        const long row = (long)b * 2048 + t;
        if (hcol < 1024)
          ((float*)qkvz)[row * 4096 + hcol] = acco[rr];
        else
          so_hi[row * 1024 + hcol - 1024] = acco[rr];
      }
    }
  }
}

// ---------------- RMS norm + gate(z) -> A2 (contiguous, in dead qv buffer) -----------
__global__ __launch_bounds__(256) void k_rmsgate(const float* __restrict__ so_hi,
                                                 const bf16_t* __restrict__ qkvz,
                                                 bf16_t* __restrict__ A2,
                                                 const float* __restrict__ norm_w) {
  long row = blockIdx.x;  // b*T + t
  int tid = threadIdx.x;
  int h = tid >> 4, j = tid & 15;
  const float* srow = (h < 8) ? (const float*)qkvz + row * 4096 + h * 128 + j * 8
                              : so_hi + row * 1024 + (h - 8) * 128 + j * 8;
  float xv[8];
  *(float4*)&xv[0] = *(const float4*)srow;
  *(float4*)&xv[4] = *(const float4*)(srow + 4);
  float ss = 0.f;
#pragma unroll
  for (int e = 0; e < 8; e++) ss += xv[e] * xv[e];
  ss += __shfl_xor(ss, 1); ss += __shfl_xor(ss, 2);
  ss += __shfl_xor(ss, 4); ss += __shfl_xor(ss, 8);
  float rinv = rsqrtf(ss * (1.0f / 128.0f) + 1e-6f);
  const bf16_t* zrow = qkvz + row * 8192 + 6144 + h * 128 + j * 8;
  bf16x8 zv = *(const bf16x8*)zrow;
  bf16x8 o;
#pragma unroll
  for (int e = 0; e < 8; e++) {
    float z = (float)zv[e];
    float gate = 1.f / (1.f + __expf(-z));
    o[e] = (bf16_t)(xv[e] * rinv * norm_w[j * 8 + e] * gate);
  }
  *(bf16x8*)(A2 + row * 2048 + h * 128 + j * 8) = o;
}

extern "C" void kernel_launch(void* const* d_in, const int* in_sizes, int n_in,
                              void* d_out, int out_size, void* d_ws, size_t ws_size,
                              hipStream_t stream) {
  const float* x      = (const float*)d_in[0];
  // d_in[1] = positions (unused)
  const float* W_qkvz = (const float*)d_in[2];
  const float* W_b    = (const float*)d_in[3];
  const float* W_a    = (const float*)d_in[4];
  const float* conv_w = (const float*)d_in[5];
  const float* norm_w = (const float*)d_in[6];
  const float* W_out  = (const float*)d_in[7];
  float* out = (float*)d_out;
  char* ws = (char*)d_ws;

  // Workspace layout (244,580,352 bytes). qkvz row (16 KB) lifecycle:
  //  [0,4K): qkv cols (dead post-conv) -> so_lo fp32[1024] (scan -> rmsgate)
  //  [4K,8K): kT stripe (tr_kv -> scan)
  //  [8K,12K): vT stripe (tr_kv -> scan)
  //  [12K,16K): z (gemm1 -> rmsgate)
  // xb/qv region: xb (cast -> gemm1), qv (conv -> scan), A2 contiguous (rmsgate -> gemm2).
  // vv: v natural (conv -> tr_kv) -> so_hi fp32 (scan -> rmsgate).
  bf16_t* qkvz  = (bf16_t*)(ws + 0);
  bf16_t* xb    = (bf16_t*)(ws + 134217728);
  bf16_t* qv    = (bf16_t*)(ws + 134217728);   // aliases xb
  bf16_t* A2    = (bf16_t*)(ws + 134217728);   // aliases qv (dead after scan)
  bf16_t* WqT   = (bf16_t*)(ws + 167772160);
  bf16_t* kv    = (bf16_t*)(ws + 167772160);   // aliases WqT
  bf16_t* vv    = (bf16_t*)(ws + 201326592);
  float*  so_hi = (float*)(ws + 201326592);    // aliases vv
  bf16_t* WoT   = (bf16_t*)(ws + 234881024);
  float*  WbT   = (float*)(ws + 243269632);
  float*  WaT   = (float*)(ws + 243400704);
  float*  beta  = (float*)(ws + 243531776);
  float*  alpha = (float*)(ws + 244056064);

  if (ws_size < 244580352) return;

  k_cast_bf16<<<8192, 256, 0, stream>>>(x, xb);
  k_transpose_cast<<<dim3(8192 / 32, 2048 / 32), dim3(32, 8), 0, stream>>>(W_qkvz, WqT, 2048, 8192);
  k_transpose_cast<<<dim3(2048 / 32, 2048 / 32), dim3(32, 8), 0, stream>>>(W_out, WoT, 2048, 2048);
  k_transpose_f32<<<8, 256, 0, stream>>>(W_b, WbT, 2048, 16);
  k_transpose_f32<<<8, 256, 0, stream>>>(W_a, WaT, 2048, 16);
  k_beta_alpha<<<512, 256, 131072, stream>>>(x, WbT, WaT, beta, alpha);
  k_gemm256<bf16_t><<<dim3(32, 32), 512, 131072, stream>>>(xb, WqT, qkvz, 8192, 2048, 2048);
  k_conv<<<8192, 256, 0, stream>>>(qkvz, conv_w, qv, kv, vv);
  k_tr_kv<<<2048, 256, 0, stream>>>(kv, vv, qkvz);
  k_scan_chunked<<<dim3(64, 4), 512, 76800, stream>>>(qv, kv, qkvz, so_hi, beta, alpha);
  k_rmsgate<<<8192, 256, 0, stream>>>(so_hi, qkvz, A2, norm_w);
  k_gemm256<float><<<dim3(8, 32), 512, 131072, stream>>>(A2, WoT, out, 2048, 2048, 2048);
  (void)in_sizes; (void)n_in; (void)out_size;
}

// Round 11
// 820.012 us; speedup vs baseline: 1.0655x; 1.0022x over previous
//
#include <hip/hip_runtime.h>
#include <hip/hip_bf16.h>

typedef __bf16 bf16_t;
typedef __attribute__((ext_vector_type(8))) __bf16 bf16x8;
typedef __attribute__((ext_vector_type(4))) float floatx4;

// Problem constants: B=4, T=2048, C=2048, H=16, D=128, QKV_DIM=6144, QKVZ=8192, BT=8192

__device__ __forceinline__ void gload16(const void* g, void* l) {
  __builtin_amdgcn_global_load_lds(
      (const __attribute__((address_space(1))) void*)g,
      (__attribute__((address_space(3))) void*)l, 16, 0, 0);
}

// ---------------- transpose + cast fp32 -> bf16 ----------------
__global__ void k_transpose_cast(const float* __restrict__ in, bf16_t* __restrict__ out,
                                 int R, int Ccols) {
  __shared__ float tile[32][33];
  int c0 = blockIdx.x * 32, r0 = blockIdx.y * 32;
  for (int i = threadIdx.y; i < 32; i += 8)
    tile[i][threadIdx.x] = in[(long)(r0 + i) * Ccols + c0 + threadIdx.x];
  __syncthreads();
  for (int i = threadIdx.y; i < 32; i += 8)
    out[(long)(c0 + i) * R + r0 + threadIdx.x] = (bf16_t)tile[threadIdx.x][i];
}

// small fp32 transpose (for W_b / W_a: 2048x16 -> 16x2048)
__global__ void k_transpose_f32(const float* __restrict__ in, float* __restrict__ out,
                                int R, int Ccols) {
  int r = blockIdx.x * blockDim.x + threadIdx.x;
  if (r < R)
    for (int c = 0; c < Ccols; ++c) out[(long)c * R + r] = in[(long)r * Ccols + c];
}

// ---------------- beta/alpha + x->bf16 cast (fused): 16 rows/block, x in LDS ----------
// Also writes xb (bf16 cast of x) from the staged LDS copy -> deletes k_cast_bf16.
__global__ __launch_bounds__(256) void k_beta_alpha(const float* __restrict__ x,
                                                    const float* __restrict__ WbT,
                                                    const float* __restrict__ WaT,
                                                    float* __restrict__ beta,
                                                    float* __restrict__ alpha,
                                                    bf16_t* __restrict__ xb) {
  extern __shared__ float xs[];  // [16][2048]
  const long row0 = (long)blockIdx.x * 16;
  const int tid = threadIdx.x;
  {
    const float4* src = (const float4*)(x + row0 * 2048);
    float4* dst = (float4*)xs;
    for (int i = tid; i < 16 * 512; i += 256) dst[i] = src[i];
  }
  __syncthreads();
  {  // fused cast: xs -> xb (coalesced bf16x8 per thread)
    bf16_t* xbrow = xb + row0 * 2048;
    for (int i = tid; i < 4096; i += 256) {
      const float4 a = *(const float4*)&xs[i * 8];
      const float4 b2 = *(const float4*)&xs[i * 8 + 4];
      bf16x8 o;
      o[0] = (bf16_t)a.x; o[1] = (bf16_t)a.y; o[2] = (bf16_t)a.z; o[3] = (bf16_t)a.w;
      o[4] = (bf16_t)b2.x; o[5] = (bf16_t)b2.y; o[6] = (bf16_t)b2.z; o[7] = (bf16_t)b2.w;
      *(bf16x8*)(xbrow + i * 8) = o;
    }
  }
  const int wv = tid >> 6, lane = tid & 63;
  for (int oo = 0; oo < 8; ++oo) {
    const int o = wv * 8 + oo;
    const float* Wrow = (o < 16) ? (WbT + (long)o * 2048) : (WaT + (long)(o - 16) * 2048);
    float acc[16];
#pragma unroll
    for (int r = 0; r < 16; ++r) acc[r] = 0.f;
    for (int kc = 0; kc < 8; ++kc) {
      const float4 w4 = *(const float4*)(Wrow + kc * 256 + lane * 4);
#pragma unroll
      for (int r = 0; r < 16; ++r) {
        const float4 xv = *(const float4*)&xs[r * 2048 + kc * 256 + lane * 4];
        acc[r] += w4.x * xv.x + w4.y * xv.y + w4.z * xv.z + w4.w * xv.w;
      }
    }
#pragma unroll
    for (int r = 0; r < 16; ++r) {
      float s = acc[r];
      for (int off = 32; off; off >>= 1) s += __shfl_down(s, off);
      if (lane == 0) {
        const long row = row0 + r;
        const int b = (int)(row >> 11), t = (int)(row & 2047);
        const float sig = 1.f / (1.f + __expf(-s));
        float* dst = (o < 16) ? beta : alpha;
        dst[((long)(b * 16 + (o & 15))) * 2048 + t] = sig;
      }
    }
  }
}

// ---------------- bf16 MFMA GEMM 256x256 (16x16x32 frags): C = A @ Bt^T --------------
// BM=BN=256, BK=64, 512 threads = 8 waves (2M x 4N), per-wave 128x64 = acc[8][4].
// LDS double-buffered 128 KiB. T2 swizzle: chunk (row,c) at (row, c ^ (row&7));
// linear gload dest + inverse-permuted global source; reads XOR. Conflict-free
// (measured 0). Pipeline: ONE barrier per K-step; STAGE(kt+1) right after barrier,
// drained by the NEXT barrier (covered by the full compute phase).
// NEW: all 24 fragment ds_reads of the K-step are issued BEFORE the MFMA groups, so
// the ks=1 reads return under the ks=0 MFMAs (LDS pipe || MFMA pipe overlap).
template <typename OUT_T>
__global__ __launch_bounds__(512, 2) void k_gemm256(const bf16_t* __restrict__ A,
                                                    const bf16_t* __restrict__ Bt,
                                                    OUT_T* __restrict__ C,
                                                    int N, int K, int lda) {
  extern __shared__ char gsm[];  // [buf0: A 32K | B 32K][buf1: A 32K | B 32K]
  const int m0 = blockIdx.y * 256, n0 = blockIdx.x * 256;
  const int tid = threadIdx.x;
  const int w = tid >> 6, l = tid & 63;
  const int wm = w >> 2, wn = w & 3;
  const int l15 = l & 15, lg = l >> 4;

  const bf16_t* asrc[4];
  const bf16_t* bsrc[4];
  int dofs[4];
#pragma unroll
  for (int t = 0; t < 4; ++t) {
    int c = t * 512 + tid;
    int row = c >> 3, cs = (c & 7) ^ (row & 7);  // pre-swizzled source chunk
    asrc[t] = A + (long)(m0 + row) * lda + cs * 8;
    bsrc[t] = Bt + (long)(n0 + row) * K + cs * 8;
    dofs[t] = c * 16;
  }

  auto STAGE = [&](int buf, int k0) {
    char* ab = gsm + buf * 65536;
    char* bb = ab + 32768;
#pragma unroll
    for (int t = 0; t < 4; ++t) {
      gload16(asrc[t] + k0, ab + dofs[t]);
      gload16(bsrc[t] + k0, bb + dofs[t]);
    }
  };

  floatx4 acc[8][4] = {};
  STAGE(0, 0);
  const int NK = K >> 6;
  for (int kt = 0; kt < NK; ++kt) {
    __syncthreads();  // drains stage(kt) [issued one full compute phase ago] + rendezvous
    if (kt + 1 < NK) STAGE((kt + 1) & 1, (kt + 1) << 6);  // prefetch; lands by next barrier
    const char* As_ = gsm + (kt & 1) * 65536;
    const char* Bs_ = As_ + 32768;
    bf16x8 af0[8], bf0[4], af1[8], bf1[4];
#pragma unroll
    for (int mi = 0; mi < 8; ++mi) {
      const int r = wm * 128 + mi * 16 + l15;
      af0[mi] = *(const bf16x8*)(As_ + r * 128 + ((lg ^ (r & 7)) << 4));
    }
#pragma unroll
    for (int ni = 0; ni < 4; ++ni) {
      const int r = wn * 64 + ni * 16 + l15;
      bf0[ni] = *(const bf16x8*)(Bs_ + r * 128 + ((lg ^ (r & 7)) << 4));
    }
#pragma unroll
    for (int mi = 0; mi < 8; ++mi) {
      const int r = wm * 128 + mi * 16 + l15;
      af1[mi] = *(const bf16x8*)(As_ + r * 128 + (((4 + lg) ^ (r & 7)) << 4));
    }
#pragma unroll
    for (int ni = 0; ni < 4; ++ni) {
      const int r = wn * 64 + ni * 16 + l15;
      bf1[ni] = *(const bf16x8*)(Bs_ + r * 128 + (((4 + lg) ^ (r & 7)) << 4));
    }
    __builtin_amdgcn_s_setprio(1);
#pragma unroll
    for (int mi = 0; mi < 8; ++mi)
#pragma unroll
      for (int ni = 0; ni < 4; ++ni)
        acc[mi][ni] = __builtin_amdgcn_mfma_f32_16x16x32_bf16(af0[mi], bf0[ni], acc[mi][ni], 0, 0, 0);
#pragma unroll
    for (int mi = 0; mi < 8; ++mi)
#pragma unroll
      for (int ni = 0; ni < 4; ++ni)
        acc[mi][ni] = __builtin_amdgcn_mfma_f32_16x16x32_bf16(af1[mi], bf1[ni], acc[mi][ni], 0, 0, 0);
    __builtin_amdgcn_s_setprio(0);
  }
  // Epilogue: C/D layout row=(l>>4)*4+r, col=l&15 [m89-verified]
  const int crow0 = m0 + wm * 128 + lg * 4;
  const int ccol = n0 + wn * 64 + l15;
#pragma unroll
  for (int mi = 0; mi < 8; ++mi)
#pragma unroll
    for (int ni = 0; ni < 4; ++ni)
#pragma unroll
      for (int r = 0; r < 4; ++r)
        C[(long)(crow0 + mi * 16 + r) * N + ccol + ni * 16] = (OUT_T)acc[mi][ni][r];
}

// ---------------- depthwise causal conv + SiLU + l2norm -> q,k,v (vectorized) ---------
__global__ __launch_bounds__(256) void k_conv(const bf16_t* __restrict__ qkvz,
                                              const float* __restrict__ conv_w,
                                              bf16_t* __restrict__ q, bf16_t* __restrict__ k,
                                              bf16_t* __restrict__ v) {
  int row = blockIdx.x;  // b*T + t
  int b = row >> 11, t = row & 2047;
  __shared__ float ys[6144];
  __shared__ float gsum[32][9];
  __shared__ float norms[32];
  const int c0 = threadIdx.x * 8;
  for (int c8 = c0; c8 < 6144; c8 += 2048) {
    bf16x8 xr[4];
#pragma unroll
    for (int w2 = 0; w2 < 4; ++w2) {
      int tt = t - 3 + w2;
      bf16x8 zr = {};
      xr[w2] = (tt >= 0) ? *(const bf16x8*)&qkvz[((long)(b * 2048 + tt)) * 8192 + c8] : zr;
    }
#pragma unroll
    for (int j = 0; j < 8; ++j) {
      float4 wv = *(const float4*)&conv_w[(c8 + j) * 4];
      float a = (float)xr[0][j] * wv.x + (float)xr[1][j] * wv.y +
                (float)xr[2][j] * wv.z + (float)xr[3][j] * wv.w;
      ys[c8 + j] = a / (1.f + __expf(-a));  // silu
    }
  }
  __syncthreads();
  {
    int g = threadIdx.x >> 3, j = threadIdx.x & 7;
    float s = 0.f;
#pragma unroll
    for (int e = 0; e < 16; ++e) {
      float yv = ys[g * 128 + j * 16 + e];
      s += yv * yv;
    }
    gsum[g][j] = s;
  }
  __syncthreads();
  if (threadIdx.x < 32) {
    float s = 0.f;
#pragma unroll
    for (int j = 0; j < 8; j++) s += gsum[threadIdx.x][j];
    norms[threadIdx.x] = 1.f / fmaxf(sqrtf(s), 1e-12f);
  }
  __syncthreads();
  for (int c8 = c0; c8 < 6144; c8 += 2048) {
    float scale;
    bf16_t* dst;
    if (c8 < 2048) {
      int h = c8 >> 7;
      scale = norms[h];
      dst = q + (((long)(b * 16 + h)) * 2048 + t) * 128 + (c8 & 127);
    } else if (c8 < 4096) {
      int h = (c8 - 2048) >> 7;
      scale = norms[16 + h];
      dst = k + (((long)(b * 16 + h)) * 2048 + t) * 128 + (c8 & 127);
    } else {
      scale = 1.f;
      int h = (c8 - 4096) >> 7;
      dst = v + (((long)(b * 16 + h)) * 2048 + t) * 128 + (c8 & 127);
    }
    bf16x8 o;
#pragma unroll
    for (int j = 0; j < 8; ++j) o[j] = (bf16_t)(ys[c8 + j] * scale);
    *(bf16x8*)dst = o;
  }
}

// ---------------- k,v natural -> kT,vT stripes inside dead qkvz region ----------------
__global__ __launch_bounds__(256) void k_tr_kv(const bf16_t* __restrict__ kv,
                                               const bf16_t* __restrict__ vv,
                                               bf16_t* __restrict__ qkvz) {
  __shared__ bf16_t t_lds[64 * 136];
  int bh = blockIdx.x >> 5, tc = blockIdx.x & 31;
  int t0 = tc * 64;
  int tid = threadIdx.x;
#pragma unroll
  for (int pass = 0; pass < 2; ++pass) {
    const bf16_t* src = (pass == 0 ? kv : vv) + (long)bh * 2048 * 128 + (long)t0 * 128;
    int r = tid >> 2, sc = (tid & 3) * 32;
    bf16x8 x0 = *(const bf16x8*)(src + (long)r * 128 + sc);
    bf16x8 x1 = *(const bf16x8*)(src + (long)r * 128 + sc + 8);
    bf16x8 x2 = *(const bf16x8*)(src + (long)r * 128 + sc + 16);
    bf16x8 x3 = *(const bf16x8*)(src + (long)r * 128 + sc + 24);
    __syncthreads();
    *(bf16x8*)&t_lds[r * 136 + sc] = x0;
    *(bf16x8*)&t_lds[r * 136 + sc + 8] = x1;
    *(bf16x8*)&t_lds[r * 136 + sc + 16] = x2;
    *(bf16x8*)&t_lds[r * 136 + sc + 24] = x3;
    __syncthreads();
    int d = tid >> 1, h2 = tid & 1;
    bf16_t* dst = qkvz + (long)(bh * 128 + d) * 8192 + (pass ? 4096 : 2048) + t0 + h2 * 32;
#pragma unroll
    for (int g = 0; g < 4; ++g) {
      bf16x8 o;
#pragma unroll
      for (int j = 0; j < 8; ++j) o[j] = t_lds[(h2 * 32 + g * 8 + j) * 136 + d];
      *(bf16x8*)(dst + g * 8) = o;
    }
  }
}

// ---------------- fused chunked gated-linear-attention scan (dv-split 4-way) ----------
// Grid (64 bh, 4 dvb), 512 threads = 8 waves. T14 async-stage: each chunk's global
// loads are issued right after the PREVIOUS chunk's b1 barrier into registers.
__global__ __launch_bounds__(512, 1) void k_scan_chunked(
    const bf16_t* __restrict__ qv, const bf16_t* __restrict__ kv,
    bf16_t* __restrict__ qkvz, float* __restrict__ so_hi,
    const float* __restrict__ beta, const float* __restrict__ alpha) {
  extern __shared__ char smem[];
  bf16_t* q_lds = (bf16_t*)smem;            // [64][136] = 17408 B
  bf16_t* kn_lds = q_lds + 8704;            // [64][136]
  bf16_t* kT_lds = kn_lds + 8704;           // [128][72] = 18432 B
  bf16_t* vT_lds = kT_lds + 9216;           // [32][72]  = 4608 B
  bf16_t* P_lds = vT_lds + 2304;            // [64][72]  = 9216 B
  bf16_t* St_lds = P_lds + 4608;            // [32][136] = 8704 B
  float* G_lds = (float*)(St_lds + 4352);   // [64]
  float* bet_lds = G_lds + 64;
  float* w_lds = bet_lds + 64;              // beta_s * exp(Gend - G_s)
  float* eG_lds = w_lds + 64;               // exp(G_t)

  const int bh = blockIdx.x, dvb = blockIdx.y;
  const int b = bh >> 4, h = bh & 15;
  const int tid = threadIdx.x;
  const int w = tid >> 6, l = tid & 63;
  const int l15 = l & 15, lg = l >> 4;
  const int g = w & 1, r = w >> 1;

  const bf16_t* qb = qv + (long)bh * 2048 * 128;
  const bf16_t* kb = kv + (long)bh * 2048 * 128;
  const bf16_t* kTg = qkvz + (long)bh * 128 * 8192 + 2048;
  const bf16_t* vTg = qkvz + (long)(bh * 128 + dvb * 32) * 8192 + 4096;
  const float* bet = beta + (long)bh * 2048;
  const float* alp = alpha + (long)bh * 2048;

  floatx4 streg[2] = {};
  for (int i = tid; i < 2176; i += 512) ((float*)St_lds)[i] = 0.f;
  __syncthreads();

  const int sr = tid >> 3, ssc = (tid & 7) * 16;    // q/kn: 64 x 128
  const int sdk = tid >> 2, ssc2 = (tid & 3) * 16;  // kT: 128 x 64
  const int svr = tid >> 3, svc = (tid & 7) * 8;    // vT: 32 x 64 (tid<256)

  // T14 prefetch registers (chunk 0)
  bf16x8 ra0, ra1, rb0, rb1, rc0, rc1, rd0 = {};
  float rbet = 0.f, ralp = 1.f;
  {
    const bf16_t* qs = qb + (long)sr * 128 + ssc;
    const bf16_t* ks = kb + (long)sr * 128 + ssc;
    const bf16_t* kts = kTg + (long)sdk * 8192 + ssc2;
    ra0 = *(const bf16x8*)qs; ra1 = *(const bf16x8*)(qs + 8);
    rb0 = *(const bf16x8*)ks; rb1 = *(const bf16x8*)(ks + 8);
    rc0 = *(const bf16x8*)kts; rc1 = *(const bf16x8*)(kts + 8);
    if (tid < 256) rd0 = *(const bf16x8*)(vTg + (long)svr * 8192 + svc);
    if (w == 0) { rbet = bet[l]; ralp = alp[l]; }
  }

  for (int c = 0; c < 32; ++c) {
    const int t0 = c * 64;
    // ---- phase A: write prefetched regs to LDS + (wave0) decay math ----
    {
      *(bf16x8*)&q_lds[sr * 136 + ssc] = ra0;
      *(bf16x8*)&q_lds[sr * 136 + ssc + 8] = ra1;
      *(bf16x8*)&kn_lds[sr * 136 + ssc] = rb0;
      *(bf16x8*)&kn_lds[sr * 136 + ssc + 8] = rb1;
      *(bf16x8*)&kT_lds[sdk * 72 + ssc2] = rc0;
      *(bf16x8*)&kT_lds[sdk * 72 + ssc2 + 8] = rc1;
      if (tid < 256) *(bf16x8*)&vT_lds[svr * 72 + svc] = rd0;
      if (w == 0) {
        float bsv = rbet;
        float la = __logf(ralp);
#pragma unroll
        for (int off = 1; off < 64; off <<= 1) {
          float xup = __shfl_up(la, off);
          if (l >= off) la += xup;
        }
        float ge = __shfl(la, 63);
        G_lds[l] = la;
        bet_lds[l] = bsv;
        w_lds[l] = bsv * __expf(ge - la);
        eG_lds[l] = __expf(la);
      }
    }
    __syncthreads();  // b1

    // ---- T14: issue next chunk's global loads (hide latency under compute) ----
    if (c + 1 < 32) {
      const int t1 = t0 + 64;
      const bf16_t* qs = qb + (long)(t1 + sr) * 128 + ssc;
      const bf16_t* ks = kb + (long)(t1 + sr) * 128 + ssc;
      const bf16_t* kts = kTg + (long)sdk * 8192 + t1 + ssc2;
      ra0 = *(const bf16x8*)qs; ra1 = *(const bf16x8*)(qs + 8);
      rb0 = *(const bf16x8*)ks; rb1 = *(const bf16x8*)(ks + 8);
      rc0 = *(const bf16x8*)kts; rc1 = *(const bf16x8*)(kts + 8);
      if (tid < 256) rd0 = *(const bf16x8*)(vTg + (long)svr * 8192 + t1 + svc);
      if (w == 0) { rbet = bet[t1 + l]; ralp = alp[t1 + l]; }
    }

    // ---- phase B: scale kT in place ----
    {
      bf16_t* p = &kT_lds[sdk * 72 + ssc2];
      bf16x8 x0 = *(bf16x8*)p, x1 = *(bf16x8*)(p + 8);
#pragma unroll
      for (int j = 0; j < 8; j++) {
        x0[j] = (bf16_t)((float)x0[j] * w_lds[ssc2 + j]);
        x1[j] = (bf16_t)((float)x1[j] * w_lds[ssc2 + 8 + j]);
      }
      *(bf16x8*)p = x0;
      *(bf16x8*)(p + 8) = x1;
    }

    // ---- phase CD: score = q K^T (2 tiles/wave), build P ----
    {
      const int mi = w >> 1;
      bf16x8 aq[4];
#pragma unroll
      for (int ks = 0; ks < 4; ks++)
        aq[ks] = *(bf16x8*)&q_lds[(mi * 16 + l15) * 136 + ks * 32 + lg * 8];
#pragma unroll
      for (int sn2 = 0; sn2 < 2; sn2++) {
        const int sn = (w & 1) * 2 + sn2;
        floatx4 sc_ = {0.f, 0.f, 0.f, 0.f};
#pragma unroll
        for (int ks = 0; ks < 4; ks++) {
          bf16x8 bk = *(bf16x8*)&kn_lds[(sn * 16 + l15) * 136 + ks * 32 + lg * 8];
          sc_ = __builtin_amdgcn_mfma_f32_16x16x32_bf16(aq[ks], bk, sc_, 0, 0, 0);
        }
        const int sl = sn * 16 + l15;
        const float gs = G_lds[sl], bs = bet_lds[sl];
#pragma unroll
        for (int rr = 0; rr < 4; rr++) {
          const int tl = mi * 16 + lg * 4 + rr;
          float val = (sl <= tl) ? sc_[rr] * __expf(G_lds[tl] - gs) * bs : 0.f;
          P_lds[tl * 72 + sl] = (bf16_t)val;
        }
      }
    }
    __syncthreads();  // b3

    // ---- phase E: out(mi=r) = exp(Gt)*(q@S_in) + P@V ; state update (ni2 = 2r,2r+1) ----
    floatx4 acco = {0.f, 0.f, 0.f, 0.f};
    {
      const int rloc = g * 16 + l15;  // local dv row (block quarter)
      bf16x8 av0 = *(bf16x8*)&vT_lds[rloc * 72 + lg * 8];
      bf16x8 av1 = *(bf16x8*)&vT_lds[rloc * 72 + 32 + lg * 8];
      floatx4 f = {0.f, 0.f, 0.f, 0.f};
#pragma unroll
      for (int ks = 0; ks < 4; ks++) {
        bf16x8 aq = *(bf16x8*)&q_lds[(r * 16 + l15) * 136 + ks * 32 + lg * 8];
        bf16x8 bs_ = *(bf16x8*)&St_lds[rloc * 136 + ks * 32 + lg * 8];
        f = __builtin_amdgcn_mfma_f32_16x16x32_bf16(aq, bs_, f, 0, 0, 0);
      }
#pragma unroll
      for (int rr = 0; rr < 4; rr++) f[rr] *= eG_lds[r * 16 + lg * 4 + rr];
#pragma unroll
      for (int ks2 = 0; ks2 < 2; ks2++) {
        bf16x8 ap = *(bf16x8*)&P_lds[(r * 16 + l15) * 72 + ks2 * 32 + lg * 8];
        f = __builtin_amdgcn_mfma_f32_16x16x32_bf16(ap, (ks2 == 0) ? av0 : av1, f, 0, 0, 0);
      }
      acco = f;
      const float dcv = eG_lds[63];
#pragma unroll
      for (int ni = 0; ni < 2; ni++) {
        const int ni2 = r * 2 + ni;
#pragma unroll
        for (int rr = 0; rr < 4; rr++) streg[ni][rr] *= dcv;
        bf16x8 bk0 = *(bf16x8*)&kT_lds[(ni2 * 16 + l15) * 72 + lg * 8];
        bf16x8 bk1 = *(bf16x8*)&kT_lds[(ni2 * 16 + l15) * 72 + 32 + lg * 8];
        streg[ni] = __builtin_amdgcn_mfma_f32_16x16x32_bf16(av0, bk0, streg[ni], 0, 0, 0);
        streg[ni] = __builtin_amdgcn_mfma_f32_16x16x32_bf16(av1, bk1, streg[ni], 0, 0, 0);
      }
    }
    __syncthreads();  // b4

    // ---- phase F: publish new state + so write ----
#pragma unroll
    for (int ni = 0; ni < 2; ni++) {
      const int ni2 = r * 2 + ni;
#pragma unroll
      for (int rr = 0; rr < 4; rr++)
        St_lds[(g * 16 + lg * 4 + rr) * 136 + ni2 * 16 + l15] = (bf16_t)streg[ni][rr];
    }
    {
      const int dvg = dvb * 32 + g * 16 + l15;
      const int hcol = h * 128 + dvg;  // 0..2047
#pragma unroll
      for (int rr = 0; rr < 4; rr++) {
        const int t = t0 + r * 16 + lg * 4 + rr;
        const long row = (long)b * 2048 + t;
        if (hcol < 1024)
          ((float*)qkvz)[row * 4096 + hcol] = acco[rr];
        else
          so_hi[row * 1024 + hcol - 1024] = acco[rr];
      }
    }
  }
}

// ---------------- RMS norm + gate(z) -> A2 (contiguous, in dead qv buffer) -----------
__global__ __launch_bounds__(256) void k_rmsgate(const float* __restrict__ so_hi,
                                                 const bf16_t* __restrict__ qkvz,
                                                 bf16_t* __restrict__ A2,
                                                 const float* __restrict__ norm_w) {
  long row = blockIdx.x;  // b*T + t
  int tid = threadIdx.x;
  int h = tid >> 4, j = tid & 15;
  const float* srow = (h < 8) ? (const float*)qkvz + row * 4096 + h * 128 + j * 8
                              : so_hi + row * 1024 + (h - 8) * 128 + j * 8;
  float xv[8];
  *(float4*)&xv[0] = *(const float4*)srow;
  *(float4*)&xv[4] = *(const float4*)(srow + 4);
  float ss = 0.f;
#pragma unroll
  for (int e = 0; e < 8; e++) ss += xv[e] * xv[e];
  ss += __shfl_xor(ss, 1); ss += __shfl_xor(ss, 2);
  ss += __shfl_xor(ss, 4); ss += __shfl_xor(ss, 8);
  float rinv = rsqrtf(ss * (1.0f / 128.0f) + 1e-6f);
  const bf16_t* zrow = qkvz + row * 8192 + 6144 + h * 128 + j * 8;
  bf16x8 zv = *(const bf16x8*)zrow;
  bf16x8 o;
#pragma unroll
  for (int e = 0; e < 8; e++) {
    float z = (float)zv[e];
    float gate = 1.f / (1.f + __expf(-z));
    o[e] = (bf16_t)(xv[e] * rinv * norm_w[j * 8 + e] * gate);
  }
  *(bf16x8*)(A2 + row * 2048 + h * 128 + j * 8) = o;
}

extern "C" void kernel_launch(void* const* d_in, const int* in_sizes, int n_in,
                              void* d_out, int out_size, void* d_ws, size_t ws_size,
                              hipStream_t stream) {
  const float* x      = (const float*)d_in[0];
  // d_in[1] = positions (unused)
  const float* W_qkvz = (const float*)d_in[2];
  const float* W_b    = (const float*)d_in[3];
  const float* W_a    = (const float*)d_in[4];
  const float* conv_w = (const float*)d_in[5];
  const float* norm_w = (const float*)d_in[6];
  const float* W_out  = (const float*)d_in[7];
  float* out = (float*)d_out;
  char* ws = (char*)d_ws;

  // Workspace layout (244,580,352 bytes). qkvz row (16 KB) lifecycle:
  //  [0,4K): qkv cols (dead post-conv) -> so_lo fp32[1024] (scan -> rmsgate)
  //  [4K,8K): kT stripe (tr_kv -> scan)
  //  [8K,12K): vT stripe (tr_kv -> scan)
  //  [12K,16K): z (gemm1 -> rmsgate)
  // xb/qv region: xb (beta_alpha -> gemm1), qv (conv -> scan), A2 (rmsgate -> gemm2).
  // vv: v natural (conv -> tr_kv) -> so_hi fp32 (scan -> rmsgate).
  bf16_t* qkvz  = (bf16_t*)(ws + 0);
  bf16_t* xb    = (bf16_t*)(ws + 134217728);
  bf16_t* qv    = (bf16_t*)(ws + 134217728);   // aliases xb
  bf16_t* A2    = (bf16_t*)(ws + 134217728);   // aliases qv (dead after scan)
  bf16_t* WqT   = (bf16_t*)(ws + 167772160);
  bf16_t* kv    = (bf16_t*)(ws + 167772160);   // aliases WqT
  bf16_t* vv    = (bf16_t*)(ws + 201326592);
  float*  so_hi = (float*)(ws + 201326592);    // aliases vv
  bf16_t* WoT   = (bf16_t*)(ws + 234881024);
  float*  WbT   = (float*)(ws + 243269632);
  float*  WaT   = (float*)(ws + 243400704);
  float*  beta  = (float*)(ws + 243531776);
  float*  alpha = (float*)(ws + 244056064);

  if (ws_size < 244580352) return;

  k_transpose_cast<<<dim3(8192 / 32, 2048 / 32), dim3(32, 8), 0, stream>>>(W_qkvz, WqT, 2048, 8192);
  k_transpose_cast<<<dim3(2048 / 32, 2048 / 32), dim3(32, 8), 0, stream>>>(W_out, WoT, 2048, 2048);
  k_transpose_f32<<<8, 256, 0, stream>>>(W_b, WbT, 2048, 16);
  k_transpose_f32<<<8, 256, 0, stream>>>(W_a, WaT, 2048, 16);
  k_beta_alpha<<<512, 256, 131072, stream>>>(x, WbT, WaT, beta, alpha, xb);
  k_gemm256<bf16_t><<<dim3(32, 32), 512, 131072, stream>>>(xb, WqT, qkvz, 8192, 2048, 2048);
  k_conv<<<8192, 256, 0, stream>>>(qkvz, conv_w, qv, kv, vv);
  k_tr_kv<<<2048, 256, 0, stream>>>(kv, vv, qkvz);
  k_scan_chunked<<<dim3(64, 4), 512, 76800, stream>>>(qv, kv, qkvz, so_hi, beta, alpha);
  k_rmsgate<<<8192, 256, 0, stream>>>(so_hi, qkvz, A2, norm_w);
  k_gemm256<float><<<dim3(8, 32), 512, 131072, stream>>>(A2, WoT, out, 2048, 2048, 2048);
  (void)in_sizes; (void)n_in; (void)out_size;
}